// Round 1
// baseline (546.554 us; speedup 1.0000x reference)
//
#include <hip/hip_runtime.h>
#include <hip/hip_bf16.h>

#define NN 6000
#define EE 192000

// ---------------- workspace layout (in 4-byte words) ----------------
// zero region [0, W_ZEND): deg, cursor, stats, sx_accum
#define W_DEG     0
#define W_CUR     6000
#define W_STATS   12000        // 6 slots x 128 (sum[64], sumsq[64])
#define W_SXACC   12768        // 4 x 192
#define W_ZEND    13536
#define W_FLAG    13536
#define W_ROWPTR  13540        // 6001
#define W_COL     19544        // 192000
#define W_X0      211544       // 6000*64
#define W_ZP1     595544
#define W_ZP2     979544
#define W_ZP3     1363544      // 6000*4
#define W_ZE1     1387544
#define W_ZE2     1771544
#define W_ZE3     2155544
#define W_S       2539544      // 6000*4
#define W_SX2     2563544      // 64
#define W_PAR     2563608      // fp32 param region (69080 floats)

struct PtrTab {
  const void* src[29];
  int off[29];
  int cnt[29];
};

__device__ __forceinline__ float bf2f(unsigned short h) {
  return __uint_as_float(((unsigned)h) << 16);
}

// ---- dtype detection: read emb_w as bf16; fp32 data reinterpreted has huge/NaN halves ----
__global__ void k_detect(const void* emb, int* flag) {
  __shared__ int bad;
  if (threadIdx.x == 0) bad = 0;
  __syncthreads();
  const unsigned short* p = (const unsigned short*)emb;
  float v0 = bf2f(p[threadIdx.x]);
  float v1 = bf2f(p[threadIdx.x + 256]);
  if (!(fabsf(v0) <= 100.f) || !(fabsf(v1) <= 100.f)) bad = 1;
  __syncthreads();
  if (threadIdx.x == 0) flag[0] = bad ? 0 : 1;   // 1 = bf16 inputs, 0 = fp32
}

// ---- convert all 29 float params into fp32 workspace region ----
__global__ void k_convert(PtrTab tab, float* base, const int* flag) {
  int b = blockIdx.x;
  const void* s = tab.src[b];
  float* d = base + tab.off[b];
  int n = tab.cnt[b];
  bool bf = (flag[0] == 1);
  if (bf) {
    const unsigned short* sp = (const unsigned short*)s;
    for (int i = threadIdx.x; i < n; i += 256) d[i] = bf2f(sp[i]);
  } else {
    const float* sp = (const float*)s;
    for (int i = threadIdx.x; i < n; i += 256) d[i] = sp[i];
  }
}

// ---- CSR build ----
__global__ void k_deg(const int* __restrict__ ei, int* __restrict__ deg) {
  int e = blockIdx.x * 256 + threadIdx.x;
  if (e < EE) atomicAdd(&deg[ei[e]], 1);
}

__global__ void k_scan(const int* __restrict__ deg, int* __restrict__ rowptr) {
  __shared__ int part[1024];
  int t = threadIdx.x;
  int base = t * 6;
  int loc[6]; int s = 0;
#pragma unroll
  for (int j = 0; j < 6; ++j) { int i = base + j; int v = (i < NN) ? deg[i] : 0; loc[j] = s; s += v; }
  part[t] = s;
  __syncthreads();
  for (int off = 1; off < 1024; off <<= 1) {
    int v = part[t];
    int add = (t >= off) ? part[t - off] : 0;
    __syncthreads();
    part[t] = v + add;
    __syncthreads();
  }
  int pre = (t == 0) ? 0 : part[t - 1];
#pragma unroll
  for (int j = 0; j < 6; ++j) { int i = base + j; if (i <= NN) rowptr[i] = pre + loc[j]; }
}

__global__ void k_scatter(const int* __restrict__ ei, const int* __restrict__ rowptr,
                          int* __restrict__ cur, int* __restrict__ col) {
  int e = blockIdx.x * 256 + threadIdx.x;
  if (e < EE) {
    int s = ei[e], d = ei[EE + e];
    int pos = atomicAdd(&cur[s], 1);
    col[rowptr[s] + pos] = d;
  }
}

// ---- embedding gather ----
__global__ void k_emb(const float* __restrict__ emb, const int* __restrict__ nt, float* __restrict__ x0) {
  int t = blockIdx.x * 256 + threadIdx.x;
  int i = t >> 6, f = t & 63;
  x0[t] = emb[nt[i] * 64 + f];
}

// ---- fused DenseSAGE layer: norm(prev) -> SpMM -> dense(wr,wl,b) -> ReLU -> BN stats ----
template <int OUT>
__global__ __launch_bounds__(256) void k_sage(
    const float* __restrict__ in_z, const float* __restrict__ in_stats,
    const float* __restrict__ wr, const float* __restrict__ wl, const float* __restrict__ bias,
    const int* __restrict__ rowptr, const int* __restrict__ col,
    float* __restrict__ out_z, float* __restrict__ out_stats) {
  __shared__ float wrT[64 * OUT + 64];
  __shared__ float wlT[64 * OUT + 64];
  __shared__ float bs[OUT];
  __shared__ float vec[4][2][64];
  __shared__ float red[4][2][OUT];
  int tid = threadIdx.x, lane = tid & 63, wv = tid >> 6;

  for (int i = tid; i < 64 * OUT; i += 256) {
    int f = i >> 6, k = i & 63;            // wr row-major [OUT][64]
    wrT[k * OUT + f] = wr[i];
    wlT[k * OUT + f] = wl[i];
  }
  if (tid < OUT) bs[tid] = bias[tid];

  float m = 0.f, r = 1.f;
  if (in_stats) {
    float s = in_stats[lane], q = in_stats[64 + lane];
    m = s * (1.f / NN);
    float v = q * (1.f / NN) - m * m;
    r = rsqrtf(v + 1e-5f);
  }
  __syncthreads();

  float accs = 0.f, accq = 0.f;
  for (int it = 0; it < 4; ++it) {
    int n = blockIdx.x * 16 + wv * 4 + it;
    bool act = (n < NN);
    float x = 0.f, aggn = 0.f;
    if (act) {
      float xz = in_z[n * 64 + lane];
      x = (xz - m) * r;
      int rs = rowptr[n], re = rowptr[n + 1];
      int cnt = re - rs;
      float sz = 0.f;
      for (int e = rs; e < re; ++e) {
        int j = col[e];
        sz += in_z[j * 64 + lane];
      }
      aggn = (sz - (float)cnt * m) * r * (1.f / (float)(cnt > 0 ? cnt : 1));
    }
    vec[wv][0][lane] = aggn;
    vec[wv][1][lane] = x;
    __syncthreads();
    float y = (lane < OUT) ? bs[lane] : 0.f;
    const float* va = &vec[wv][0][0];
    const float* vx = &vec[wv][1][0];
#pragma unroll
    for (int kk = 0; kk < 16; ++kk) {
      const float4 a4 = *(const float4*)(va + kk * 4);
      const float4 x4 = *(const float4*)(vx + kk * 4);
      int k0 = kk * 4;
      y += a4.x * wrT[(k0 + 0) * OUT + lane]; y += x4.x * wlT[(k0 + 0) * OUT + lane];
      y += a4.y * wrT[(k0 + 1) * OUT + lane]; y += x4.y * wlT[(k0 + 1) * OUT + lane];
      y += a4.z * wrT[(k0 + 2) * OUT + lane]; y += x4.z * wlT[(k0 + 2) * OUT + lane];
      y += a4.w * wrT[(k0 + 3) * OUT + lane]; y += x4.w * wlT[(k0 + 3) * OUT + lane];
    }
    float z = fmaxf(y, 0.f);
    if (act && lane < OUT) {
      out_z[n * OUT + lane] = z;
      accs += z;
      accq += z * z;
    }
    __syncthreads();
  }
  if (lane < OUT) { red[wv][0][lane] = accs; red[wv][1][lane] = accq; }
  __syncthreads();
  if (tid < OUT) {
    float s = red[0][0][tid] + red[1][0][tid] + red[2][0][tid] + red[3][0][tid];
    float q = red[0][1][tid] + red[1][1][tid] + red[2][1][tid] + red[3][1][tid];
    atomicAdd(&out_stats[tid], s);
    atomicAdd(&out_stats[64 + tid], q);
  }
}

// ---- pool head: plin -> ReLU -> s; softmax(s); accumulate s_x = ssm^T @ xe ----
__global__ __launch_bounds__(256) void k_pool(
    const float* __restrict__ zp1, const float* __restrict__ zp2, const float* __restrict__ zp3,
    const float* __restrict__ sp1, const float* __restrict__ sp2, const float* __restrict__ sp3,
    const float* __restrict__ ze1, const float* __restrict__ ze2, const float* __restrict__ ze3,
    const float* __restrict__ se1, const float* __restrict__ se2, const float* __restrict__ se3,
    const float* __restrict__ plw, const float* __restrict__ plb,
    float* __restrict__ s_out, float* __restrict__ sx_acc) {
  __shared__ float red[4][12][64];
  int tid = threadIdx.x, lane = tid & 63, wv = tid >> 6;

  float mp1 = sp1[lane] * (1.f / NN); float rp1 = rsqrtf(sp1[64 + lane] * (1.f / NN) - mp1 * mp1 + 1e-5f);
  float mp2 = sp2[lane] * (1.f / NN); float rp2 = rsqrtf(sp2[64 + lane] * (1.f / NN) - mp2 * mp2 + 1e-5f);
  float mp3 = 0.f, rp3 = 1.f;
  if (lane < 4) { mp3 = sp3[lane] * (1.f / NN); rp3 = rsqrtf(sp3[64 + lane] * (1.f / NN) - mp3 * mp3 + 1e-5f); }
  float me1 = se1[lane] * (1.f / NN); float re1 = rsqrtf(se1[64 + lane] * (1.f / NN) - me1 * me1 + 1e-5f);
  float me2 = se2[lane] * (1.f / NN); float re2 = rsqrtf(se2[64 + lane] * (1.f / NN) - me2 * me2 + 1e-5f);
  float me3 = se3[lane] * (1.f / NN); float re3 = rsqrtf(se3[64 + lane] * (1.f / NN) - me3 * me3 + 1e-5f);

  float w0a = plw[0 * 132 + lane], w0b = plw[0 * 132 + 64 + lane], w0c = (lane < 4) ? plw[0 * 132 + 128 + lane] : 0.f;
  float w1a = plw[1 * 132 + lane], w1b = plw[1 * 132 + 64 + lane], w1c = (lane < 4) ? plw[1 * 132 + 128 + lane] : 0.f;
  float w2a = plw[2 * 132 + lane], w2b = plw[2 * 132 + 64 + lane], w2c = (lane < 4) ? plw[2 * 132 + 128 + lane] : 0.f;
  float w3a = plw[3 * 132 + lane], w3b = plw[3 * 132 + 64 + lane], w3c = (lane < 4) ? plw[3 * 132 + 128 + lane] : 0.f;
  float pb0 = plb[0], pb1v = plb[1], pb2v = plb[2], pb3v = plb[3];

  float acc[12];
#pragma unroll
  for (int u = 0; u < 12; ++u) acc[u] = 0.f;

  for (int it = 0; it < 4; ++it) {
    int n = blockIdx.x * 16 + wv * 4 + it;
    bool act = (n < NN);
    if (act) {
      float a = (zp1[n * 64 + lane] - mp1) * rp1;
      float b = (zp2[n * 64 + lane] - mp2) * rp2;
      float c = (lane < 4) ? ((zp3[n * 4 + lane] - mp3) * rp3) : 0.f;
      float p0 = a * w0a + b * w0b + c * w0c;
      float p1 = a * w1a + b * w1b + c * w1c;
      float p2 = a * w2a + b * w2b + c * w2c;
      float p3 = a * w3a + b * w3b + c * w3c;
#pragma unroll
      for (int off = 1; off < 64; off <<= 1) {
        p0 += __shfl_xor(p0, off);
        p1 += __shfl_xor(p1, off);
        p2 += __shfl_xor(p2, off);
        p3 += __shfl_xor(p3, off);
      }
      float s0 = fmaxf(p0 + pb0, 0.f), s1 = fmaxf(p1 + pb1v, 0.f);
      float s2 = fmaxf(p2 + pb2v, 0.f), s3 = fmaxf(p3 + pb3v, 0.f);
      if (lane < 4) {
        float sv = (lane == 0) ? s0 : (lane == 1) ? s1 : (lane == 2) ? s2 : s3;
        s_out[n * 4 + lane] = sv;
      }
      float mx = fmaxf(fmaxf(s0, s1), fmaxf(s2, s3));
      float e0 = __expf(s0 - mx), e1 = __expf(s1 - mx), e2 = __expf(s2 - mx), e3 = __expf(s3 - mx);
      float inv = 1.f / (e0 + e1 + e2 + e3);
      e0 *= inv; e1 *= inv; e2 *= inv; e3 *= inv;
      float x1 = (ze1[n * 64 + lane] - me1) * re1;
      float x2 = (ze2[n * 64 + lane] - me2) * re2;
      float x3 = (ze3[n * 64 + lane] - me3) * re3;
      acc[0] += e0 * x1; acc[1] += e0 * x2; acc[2] += e0 * x3;
      acc[3] += e1 * x1; acc[4] += e1 * x2; acc[5] += e1 * x3;
      acc[6] += e2 * x1; acc[7] += e2 * x2; acc[8] += e2 * x3;
      acc[9] += e3 * x1; acc[10] += e3 * x2; acc[11] += e3 * x3;
    }
  }
#pragma unroll
  for (int u = 0; u < 12; ++u) red[wv][u][lane] = acc[u];
  __syncthreads();
  for (int u = tid; u < 768; u += 256) {
    int f = u & 63, q = u >> 6;
    float v = red[0][q][f] + red[1][q][f] + red[2][q][f] + red[3][q][f];
    int k = q / 3, slot = q - 3 * k;
    atomicAdd(&sx_acc[k * 192 + slot * 64 + f], v);
  }
}

// ---- cluster MLP: lin1+ReLU then lin2 on the 4x192 pooled matrix ----
__global__ void k_mlp(const float* __restrict__ sx, const float* __restrict__ l1w, const float* __restrict__ l1b,
                      const float* __restrict__ l2w, const float* __restrict__ l2b, float* __restrict__ sx2) {
  __shared__ float tl[4][64];
  int tid = threadIdx.x;
  int k = tid >> 6, f = tid & 63;
  float v = l1b[f];
  for (int c = 0; c < 192; ++c) v += sx[k * 192 + c] * l1w[f * 192 + c];
  tl[k][f] = fmaxf(v, 0.f);
  __syncthreads();
  if (tid < 64) {
    int kk = tid >> 4, o = tid & 15;
    float u = l2b[o];
#pragma unroll
    for (int j = 0; j < 64; ++j) u += tl[kk][j] * l2w[o * 64 + j];
    sx2[kk * 16 + o] = u;
  }
}

// ---- final: x_embed = embl(xe); argmax(s); out = lin3([x_embed, s_x2[idx]]) ----
__global__ __launch_bounds__(256) void k_final(
    const float* __restrict__ ze1, const float* __restrict__ ze2, const float* __restrict__ ze3,
    const float* __restrict__ se1, const float* __restrict__ se2, const float* __restrict__ se3,
    const float* __restrict__ ew, const float* __restrict__ ebv,
    const float* __restrict__ l3w, const float* __restrict__ l3b,
    const float* __restrict__ s_out, const float* __restrict__ sx2,
    const int* __restrict__ flag, void* __restrict__ out) {
  __shared__ float ewT[192 * 32];
  __shared__ float l3T[48 * 16];
  __shared__ float ebs[32], l3bs[16];
  __shared__ float xev[4][192];
  __shared__ float xed[4][32];
  int tid = threadIdx.x, lane = tid & 63, wv = tid >> 6;

  for (int i = tid; i < 6144; i += 256) { int cp = i / 192, c = i - cp * 192; ewT[c * 32 + cp] = ew[i]; }
  for (int i = tid; i < 768; i += 256) { int o = i / 48, j = i - o * 48; l3T[j * 16 + o] = l3w[i]; }
  if (tid < 32) ebs[tid] = ebv[tid];
  if (tid < 16) l3bs[tid] = l3b[tid];

  float me1 = se1[lane] * (1.f / NN); float re1 = rsqrtf(se1[64 + lane] * (1.f / NN) - me1 * me1 + 1e-5f);
  float me2 = se2[lane] * (1.f / NN); float re2 = rsqrtf(se2[64 + lane] * (1.f / NN) - me2 * me2 + 1e-5f);
  float me3 = se3[lane] * (1.f / NN); float re3 = rsqrtf(se3[64 + lane] * (1.f / NN) - me3 * me3 + 1e-5f);
  bool bf = (flag[0] == 1);
  __syncthreads();

  int h = lane >> 5, L = lane & 31;
  for (int it = 0; it < 4; ++it) {
    int n = blockIdx.x * 16 + wv * 4 + it;
    bool act = (n < NN);
    float x1 = 0.f, x2 = 0.f, x3 = 0.f;
    if (act) {
      x1 = (ze1[n * 64 + lane] - me1) * re1;
      x2 = (ze2[n * 64 + lane] - me2) * re2;
      x3 = (ze3[n * 64 + lane] - me3) * re3;
    }
    xev[wv][lane] = x1;
    xev[wv][64 + lane] = x2;
    xev[wv][128 + lane] = x3;
    __syncthreads();
    float v = (h == 0) ? ebs[L] : 0.f;
    int cb = h * 96;
#pragma unroll
    for (int c4 = 0; c4 < 24; ++c4) {
      const float4 xv = *(const float4*)&xev[wv][cb + c4 * 4];
      int c0 = cb + c4 * 4;
      v += xv.x * ewT[(c0 + 0) * 32 + L];
      v += xv.y * ewT[(c0 + 1) * 32 + L];
      v += xv.z * ewT[(c0 + 2) * 32 + L];
      v += xv.w * ewT[(c0 + 3) * 32 + L];
    }
    v += __shfl_xor(v, 32);
    if (h == 0) xed[wv][L] = v;
    __syncthreads();
    if (act && lane < 16) {
      int idx = 0; float best = s_out[n * 4 + 0];
      float c1 = s_out[n * 4 + 1]; if (c1 > best) { best = c1; idx = 1; }
      float c2 = s_out[n * 4 + 2]; if (c2 > best) { best = c2; idx = 2; }
      float c3 = s_out[n * 4 + 3]; if (c3 > best) { best = c3; idx = 3; }
      float racc = l3bs[lane];
#pragma unroll
      for (int j = 0; j < 32; ++j) racc += xed[wv][j] * l3T[j * 16 + lane];
      const float* sxr = sx2 + idx * 16;
#pragma unroll
      for (int j = 0; j < 16; ++j) racc += sxr[j] * l3T[(32 + j) * 16 + lane];
      if (bf) ((__hip_bfloat16*)out)[n * 16 + lane] = __float2bfloat16(racc);
      else    ((float*)out)[n * 16 + lane] = racc;
    }
    __syncthreads();
  }
}

extern "C" void kernel_launch(void* const* d_in, const int* in_sizes, int n_in,
                              void* d_out, int out_size, void* d_ws, size_t ws_size,
                              hipStream_t stream) {
  float* F = (float*)d_ws;
  int* I = (int*)d_ws;

  static const int pcnt[29] = {6400, 4096, 4096, 64, 4096, 4096, 64, 256, 256, 4, 528, 4,
                               4096, 4096, 64, 4096, 4096, 64, 4096, 4096, 64,
                               12288, 64, 1024, 16, 6144, 32, 768, 16};
  int poff[29];
  { int a = 0; for (int i = 0; i < 29; ++i) { poff[i] = a; a += pcnt[i]; } }

  PtrTab tab;
  for (int i = 0; i < 29; ++i) { tab.src[i] = d_in[i]; tab.off[i] = poff[i]; tab.cnt[i] = pcnt[i]; }

  const int* ei = (const int*)d_in[29];
  const int* nt = (const int*)d_in[30];

  int* deg = I + W_DEG;
  int* cur = I + W_CUR;
  int* rowptr = I + W_ROWPTR;
  int* col = I + W_COL;
  int* flag = I + W_FLAG;
  float* st = F + W_STATS;     // st + 128*i for slot i
  float* sxacc = F + W_SXACC;
  float* x0 = F + W_X0;
  float* zp1 = F + W_ZP1; float* zp2 = F + W_ZP2; float* zp3 = F + W_ZP3;
  float* ze1 = F + W_ZE1; float* ze2 = F + W_ZE2; float* ze3 = F + W_ZE3;
  float* sbuf = F + W_S;
  float* sx2 = F + W_SX2;
  float* P = F + W_PAR;
#define PP(i) (P + poff[i])

  hipMemsetAsync(d_ws, 0, (size_t)W_ZEND * 4, stream);
  k_detect<<<1, 256, 0, stream>>>(d_in[0], flag);
  k_convert<<<29, 256, 0, stream>>>(tab, P, flag);
  k_deg<<<750, 256, 0, stream>>>(ei, deg);
  k_scan<<<1, 1024, 0, stream>>>(deg, rowptr);
  k_scatter<<<750, 256, 0, stream>>>(ei, rowptr, cur, col);
  k_emb<<<1500, 256, 0, stream>>>(PP(0), nt, x0);

  // pool GNN
  k_sage<64><<<376, 256, 0, stream>>>(x0, nullptr, PP(1), PP(2), PP(3), rowptr, col, zp1, st + 0 * 128);
  k_sage<64><<<376, 256, 0, stream>>>(zp1, st + 0 * 128, PP(4), PP(5), PP(6), rowptr, col, zp2, st + 1 * 128);
  k_sage<4><<<376, 256, 0, stream>>>(zp2, st + 1 * 128, PP(7), PP(8), PP(9), rowptr, col, zp3, st + 2 * 128);
  // embed GNN
  k_sage<64><<<376, 256, 0, stream>>>(x0, nullptr, PP(12), PP(13), PP(14), rowptr, col, ze1, st + 3 * 128);
  k_sage<64><<<376, 256, 0, stream>>>(ze1, st + 3 * 128, PP(15), PP(16), PP(17), rowptr, col, ze2, st + 4 * 128);
  k_sage<64><<<376, 256, 0, stream>>>(ze2, st + 4 * 128, PP(18), PP(19), PP(20), rowptr, col, ze3, st + 5 * 128);

  k_pool<<<376, 256, 0, stream>>>(zp1, zp2, zp3, st + 0 * 128, st + 1 * 128, st + 2 * 128,
                                  ze1, ze2, ze3, st + 3 * 128, st + 4 * 128, st + 5 * 128,
                                  PP(10), PP(11), sbuf, sxacc);
  k_mlp<<<1, 256, 0, stream>>>(sxacc, PP(21), PP(22), PP(23), PP(24), sx2);
  k_final<<<376, 256, 0, stream>>>(ze1, ze2, ze3, st + 3 * 128, st + 4 * 128, st + 5 * 128,
                                   PP(25), PP(26), PP(27), PP(28), sbuf, sx2, flag, d_out);
}

// Round 2
// 450.250 us; speedup vs baseline: 1.2139x; 1.2139x over previous
//
#include <hip/hip_runtime.h>
#include <hip/hip_bf16.h>

#define NN 6000
#define EE 192000

// ---------------- workspace layout (in 4-byte words) ----------------
#define W_DEG     0
#define W_CUR     6000
#define W_STATS   12000        // 6 slots x 128 (sum[64], sumsq[64])
#define W_SXACC   12768        // 4 x 192
#define W_ZEND    13536
#define W_FLAG    13536
#define W_ROWPTR  13540        // 6001
#define W_COL     19544        // 192000
#define W_X0      211544       // 6000*64
#define W_ZP1     595544
#define W_ZP2     979544
#define W_ZP3     1363544      // 6000*4
#define W_ZE1     1387544
#define W_ZE2     1771544
#define W_ZE3     2155544
#define W_S       2539544      // 6000*4
#define W_SX2     2563544      // 64
#define W_PAR     2563608      // fp32 param region

struct PtrTab {
  const void* src[29];
  int off[29];
  int cnt[29];
};

__device__ __forceinline__ float bf2f(unsigned short h) {
  return __uint_as_float(((unsigned)h) << 16);
}

// ---- dtype detection ----
__global__ void k_detect(const void* emb, int* flag) {
  __shared__ int bad;
  if (threadIdx.x == 0) bad = 0;
  __syncthreads();
  const unsigned short* p = (const unsigned short*)emb;
  float v0 = bf2f(p[threadIdx.x]);
  float v1 = bf2f(p[threadIdx.x + 256]);
  if (!(fabsf(v0) <= 100.f) || !(fabsf(v1) <= 100.f)) bad = 1;
  __syncthreads();
  if (threadIdx.x == 0) flag[0] = bad ? 0 : 1;   // 1 = bf16 inputs, 0 = fp32
}

// ---- convert params to fp32 workspace ----
__global__ void k_convert(PtrTab tab, float* base, const int* flag) {
  int b = blockIdx.x;
  const void* s = tab.src[b];
  float* d = base + tab.off[b];
  int n = tab.cnt[b];
  bool bf = (flag[0] == 1);
  if (bf) {
    const unsigned short* sp = (const unsigned short*)s;
    for (int i = threadIdx.x; i < n; i += 256) d[i] = bf2f(sp[i]);
  } else {
    const float* sp = (const float*)s;
    for (int i = threadIdx.x; i < n; i += 256) d[i] = sp[i];
  }
}

// ---- CSR build ----
__global__ void k_deg(const int* __restrict__ ei, int* __restrict__ deg) {
  int e = blockIdx.x * 256 + threadIdx.x;
  if (e < EE) atomicAdd(&deg[ei[e]], 1);
}

__global__ void k_scan(const int* __restrict__ deg, int* __restrict__ rowptr) {
  __shared__ int part[1024];
  int t = threadIdx.x;
  int base = t * 6;
  int loc[6]; int s = 0;
#pragma unroll
  for (int j = 0; j < 6; ++j) { int i = base + j; int v = (i < NN) ? deg[i] : 0; loc[j] = s; s += v; }
  part[t] = s;
  __syncthreads();
  for (int off = 1; off < 1024; off <<= 1) {
    int v = part[t];
    int add = (t >= off) ? part[t - off] : 0;
    __syncthreads();
    part[t] = v + add;
    __syncthreads();
  }
  int pre = (t == 0) ? 0 : part[t - 1];
#pragma unroll
  for (int j = 0; j < 6; ++j) { int i = base + j; if (i <= NN) rowptr[i] = pre + loc[j]; }
}

__global__ void k_scatter(const int* __restrict__ ei, const int* __restrict__ rowptr,
                          int* __restrict__ cur, int* __restrict__ col) {
  int e = blockIdx.x * 256 + threadIdx.x;
  if (e < EE) {
    int s = ei[e], d = ei[EE + e];
    int pos = atomicAdd(&cur[s], 1);
    col[rowptr[s] + pos] = d;
  }
}

// ---- embedding gather ----
__global__ void k_emb(const float* __restrict__ emb, const int* __restrict__ nt, float* __restrict__ x0) {
  int t = blockIdx.x * 256 + threadIdx.x;
  int i = t >> 6, f = t & 63;
  x0[t] = emb[nt[i] * 64 + f];
}

// ---- fused DenseSAGE layer: one node per wave, no intra-wave barriers ----
// grid = 1500 blocks x 256 (4 waves) -> 6000 nodes exactly
template <int OUT>
__global__ __launch_bounds__(256) void k_sage(
    const float* __restrict__ in_z, const float* __restrict__ in_stats,
    const float* __restrict__ wr, const float* __restrict__ wl, const float* __restrict__ bias,
    const int* __restrict__ rowptr, const int* __restrict__ col,
    float* __restrict__ out_z, float* __restrict__ out_stats) {
  __shared__ float wrT[64 * (OUT + 1)];   // padded stride: bank (k+f)%32, conflict-free
  __shared__ float wlT[64 * (OUT + 1)];
  __shared__ float bs[OUT];
  __shared__ float vec[4][2][64];
  __shared__ float red[4][2][OUT];
  int tid = threadIdx.x, lane = tid & 63, wv = tid >> 6;

  for (int i = tid; i < 64 * OUT; i += 256) {
    int f = i >> 6, k = i & 63;            // wr row-major [OUT][64]
    wrT[k * (OUT + 1) + f] = wr[i];
    wlT[k * (OUT + 1) + f] = wl[i];
  }
  if (tid < OUT) bs[tid] = bias[tid];

  float m = 0.f, r = 1.f;
  if (in_stats) {
    float s = in_stats[lane], q = in_stats[64 + lane];
    m = s * (1.f / NN);
    r = rsqrtf(q * (1.f / NN) - m * m + 1e-5f);
  }
  __syncthreads();   // weights staged; only barrier in the kernel

  int n = blockIdx.x * 4 + wv;
  float xz = in_z[n * 64 + lane];
  float x = (xz - m) * r;
  int rs = __builtin_amdgcn_readfirstlane(rowptr[n]);
  int re = __builtin_amdgcn_readfirstlane(rowptr[n + 1]);
  int cnt = re - rs;
  float sz = 0.f;
  int e = rs;
  for (; e + 4 <= re; e += 4) {
    int j0 = col[e], j1 = col[e + 1], j2 = col[e + 2], j3 = col[e + 3];
    float v0 = in_z[j0 * 64 + lane];
    float v1 = in_z[j1 * 64 + lane];
    float v2 = in_z[j2 * 64 + lane];
    float v3 = in_z[j3 * 64 + lane];
    sz += (v0 + v1) + (v2 + v3);
  }
  for (; e < re; ++e) sz += in_z[col[e] * 64 + lane];
  float aggn = (sz - (float)cnt * m) * r / (float)(cnt > 0 ? cnt : 1);

  vec[wv][0][lane] = aggn;
  vec[wv][1][lane] = x;
  // wave-synchronous LDS: write->read within one wave64, no barrier needed
  int ol = lane & (OUT - 1);               // clamp index for OUT<64 lanes
  float y = bs[ol];
  const float* va = &vec[wv][0][0];
  const float* vx = &vec[wv][1][0];
#pragma unroll
  for (int kk = 0; kk < 16; ++kk) {
    const float4 a4 = *(const float4*)(va + kk * 4);
    const float4 x4 = *(const float4*)(vx + kk * 4);
    int k0 = kk * 4;
    y += a4.x * wrT[(k0 + 0) * (OUT + 1) + ol]; y += x4.x * wlT[(k0 + 0) * (OUT + 1) + ol];
    y += a4.y * wrT[(k0 + 1) * (OUT + 1) + ol]; y += x4.y * wlT[(k0 + 1) * (OUT + 1) + ol];
    y += a4.z * wrT[(k0 + 2) * (OUT + 1) + ol]; y += x4.z * wlT[(k0 + 2) * (OUT + 1) + ol];
    y += a4.w * wrT[(k0 + 3) * (OUT + 1) + ol]; y += x4.w * wlT[(k0 + 3) * (OUT + 1) + ol];
  }
  float z = fmaxf(y, 0.f);
  if (lane < OUT) {
    out_z[n * OUT + lane] = z;
    red[wv][0][lane] = z;
    red[wv][1][lane] = z * z;
  }
  __syncthreads();
  if (tid < OUT) {
    float s = red[0][0][tid] + red[1][0][tid] + red[2][0][tid] + red[3][0][tid];
    float q = red[0][1][tid] + red[1][1][tid] + red[2][1][tid] + red[3][1][tid];
    atomicAdd(&out_stats[tid], s);
    atomicAdd(&out_stats[64 + tid], q);
  }
}

// ---- pool head: plin -> ReLU -> s; softmax(s); accumulate s_x = ssm^T @ xe ----
// grid = 750 blocks x 256, 2 nodes per wave
__global__ __launch_bounds__(256) void k_pool(
    const float* __restrict__ zp1, const float* __restrict__ zp2, const float* __restrict__ zp3,
    const float* __restrict__ sp1, const float* __restrict__ sp2, const float* __restrict__ sp3,
    const float* __restrict__ ze1, const float* __restrict__ ze2, const float* __restrict__ ze3,
    const float* __restrict__ se1, const float* __restrict__ se2, const float* __restrict__ se3,
    const float* __restrict__ plw, const float* __restrict__ plb,
    float* __restrict__ s_out, float* __restrict__ sx_acc) {
  __shared__ float red[4][12][64];
  int tid = threadIdx.x, lane = tid & 63, wv = tid >> 6;

  float mp1 = sp1[lane] * (1.f / NN); float rp1 = rsqrtf(sp1[64 + lane] * (1.f / NN) - mp1 * mp1 + 1e-5f);
  float mp2 = sp2[lane] * (1.f / NN); float rp2 = rsqrtf(sp2[64 + lane] * (1.f / NN) - mp2 * mp2 + 1e-5f);
  float mp3 = 0.f, rp3 = 1.f;
  if (lane < 4) { mp3 = sp3[lane] * (1.f / NN); rp3 = rsqrtf(sp3[64 + lane] * (1.f / NN) - mp3 * mp3 + 1e-5f); }
  float me1 = se1[lane] * (1.f / NN); float re1 = rsqrtf(se1[64 + lane] * (1.f / NN) - me1 * me1 + 1e-5f);
  float me2 = se2[lane] * (1.f / NN); float re2 = rsqrtf(se2[64 + lane] * (1.f / NN) - me2 * me2 + 1e-5f);
  float me3 = se3[lane] * (1.f / NN); float re3 = rsqrtf(se3[64 + lane] * (1.f / NN) - me3 * me3 + 1e-5f);

  float w0a = plw[0 * 132 + lane], w0b = plw[0 * 132 + 64 + lane], w0c = (lane < 4) ? plw[0 * 132 + 128 + lane] : 0.f;
  float w1a = plw[1 * 132 + lane], w1b = plw[1 * 132 + 64 + lane], w1c = (lane < 4) ? plw[1 * 132 + 128 + lane] : 0.f;
  float w2a = plw[2 * 132 + lane], w2b = plw[2 * 132 + 64 + lane], w2c = (lane < 4) ? plw[2 * 132 + 128 + lane] : 0.f;
  float w3a = plw[3 * 132 + lane], w3b = plw[3 * 132 + 64 + lane], w3c = (lane < 4) ? plw[3 * 132 + 128 + lane] : 0.f;
  float pb0 = plb[0], pb1v = plb[1], pb2v = plb[2], pb3v = plb[3];

  float acc[12];
#pragma unroll
  for (int u = 0; u < 12; ++u) acc[u] = 0.f;

#pragma unroll
  for (int it = 0; it < 2; ++it) {
    int n = blockIdx.x * 8 + wv * 2 + it;
    float a = (zp1[n * 64 + lane] - mp1) * rp1;
    float b = (zp2[n * 64 + lane] - mp2) * rp2;
    float c = (lane < 4) ? ((zp3[n * 4 + lane] - mp3) * rp3) : 0.f;
    float p0 = a * w0a + b * w0b + c * w0c;
    float p1 = a * w1a + b * w1b + c * w1c;
    float p2 = a * w2a + b * w2b + c * w2c;
    float p3 = a * w3a + b * w3b + c * w3c;
#pragma unroll
    for (int off = 1; off < 64; off <<= 1) {
      p0 += __shfl_xor(p0, off);
      p1 += __shfl_xor(p1, off);
      p2 += __shfl_xor(p2, off);
      p3 += __shfl_xor(p3, off);
    }
    float s0 = fmaxf(p0 + pb0, 0.f), s1 = fmaxf(p1 + pb1v, 0.f);
    float s2 = fmaxf(p2 + pb2v, 0.f), s3 = fmaxf(p3 + pb3v, 0.f);
    if (lane < 4) {
      float sv = (lane == 0) ? s0 : (lane == 1) ? s1 : (lane == 2) ? s2 : s3;
      s_out[n * 4 + lane] = sv;
    }
    float mx = fmaxf(fmaxf(s0, s1), fmaxf(s2, s3));
    float e0 = __expf(s0 - mx), e1 = __expf(s1 - mx), e2 = __expf(s2 - mx), e3 = __expf(s3 - mx);
    float inv = 1.f / (e0 + e1 + e2 + e3);
    e0 *= inv; e1 *= inv; e2 *= inv; e3 *= inv;
    float x1 = (ze1[n * 64 + lane] - me1) * re1;
    float x2 = (ze2[n * 64 + lane] - me2) * re2;
    float x3 = (ze3[n * 64 + lane] - me3) * re3;
    acc[0] += e0 * x1; acc[1] += e0 * x2; acc[2] += e0 * x3;
    acc[3] += e1 * x1; acc[4] += e1 * x2; acc[5] += e1 * x3;
    acc[6] += e2 * x1; acc[7] += e2 * x2; acc[8] += e2 * x3;
    acc[9] += e3 * x1; acc[10] += e3 * x2; acc[11] += e3 * x3;
  }
#pragma unroll
  for (int u = 0; u < 12; ++u) red[wv][u][lane] = acc[u];
  __syncthreads();
  for (int u = tid; u < 768; u += 256) {
    int f = u & 63, q = u >> 6;
    float v = red[0][q][f] + red[1][q][f] + red[2][q][f] + red[3][q][f];
    int k = q / 3, slot = q - 3 * k;
    atomicAdd(&sx_acc[k * 192 + slot * 64 + f], v);
  }
}

// ---- cluster MLP ----
__global__ void k_mlp(const float* __restrict__ sx, const float* __restrict__ l1w, const float* __restrict__ l1b,
                      const float* __restrict__ l2w, const float* __restrict__ l2b, float* __restrict__ sx2) {
  __shared__ float tl[4][64];
  int tid = threadIdx.x;
  int k = tid >> 6, f = tid & 63;
  float v = l1b[f];
  for (int c = 0; c < 192; ++c) v += sx[k * 192 + c] * l1w[f * 192 + c];
  tl[k][f] = fmaxf(v, 0.f);
  __syncthreads();
  if (tid < 64) {
    int kk = tid >> 4, o = tid & 15;
    float u = l2b[o];
#pragma unroll
    for (int j = 0; j < 64; ++j) u += tl[kk][j] * l2w[o * 64 + j];
    sx2[kk * 16 + o] = u;
  }
}

// ---- final: x_embed = embl(xe); argmax(s); out = lin3([x_embed, s_x2[idx]]) ----
// grid = 1500 blocks x 256, 1 node per wave
__global__ __launch_bounds__(256) void k_final(
    const float* __restrict__ ze1, const float* __restrict__ ze2, const float* __restrict__ ze3,
    const float* __restrict__ se1, const float* __restrict__ se2, const float* __restrict__ se3,
    const float* __restrict__ ew, const float* __restrict__ ebv,
    const float* __restrict__ l3w, const float* __restrict__ l3b,
    const float* __restrict__ s_out, const float* __restrict__ sx2,
    const int* __restrict__ flag, void* __restrict__ out) {
  __shared__ float ewT[192 * 33];          // padded: bank (c+cp)%32
  __shared__ float l3T[48 * 17];
  __shared__ float ebs[32], l3bs[16];
  __shared__ float xev[4][192];
  __shared__ float xed[4][32];
  int tid = threadIdx.x, lane = tid & 63, wv = tid >> 6;

  for (int i = tid; i < 6144; i += 256) { int cp = i / 192, c = i - cp * 192; ewT[c * 33 + cp] = ew[i]; }
  for (int i = tid; i < 768; i += 256) { int o = i / 48, j = i - o * 48; l3T[j * 17 + o] = l3w[i]; }
  if (tid < 32) ebs[tid] = ebv[tid];
  if (tid < 16) l3bs[tid] = l3b[tid];

  float me1 = se1[lane] * (1.f / NN); float re1 = rsqrtf(se1[64 + lane] * (1.f / NN) - me1 * me1 + 1e-5f);
  float me2 = se2[lane] * (1.f / NN); float re2 = rsqrtf(se2[64 + lane] * (1.f / NN) - me2 * me2 + 1e-5f);
  float me3 = se3[lane] * (1.f / NN); float re3 = rsqrtf(se3[64 + lane] * (1.f / NN) - me3 * me3 + 1e-5f);
  bool bf = (flag[0] == 1);
  __syncthreads();   // staging barrier; everything below is wave-private

  int h = lane >> 5, L = lane & 31;
  int n = blockIdx.x * 4 + wv;
  float x1 = (ze1[n * 64 + lane] - me1) * re1;
  float x2 = (ze2[n * 64 + lane] - me2) * re2;
  float x3 = (ze3[n * 64 + lane] - me3) * re3;
  xev[wv][lane] = x1;
  xev[wv][64 + lane] = x2;
  xev[wv][128 + lane] = x3;
  // wave-synchronous LDS, no barrier
  float v = (h == 0) ? ebs[L] : 0.f;
  int cb = h * 96;
#pragma unroll
  for (int c4 = 0; c4 < 24; ++c4) {
    const float4 xv = *(const float4*)&xev[wv][cb + c4 * 4];
    int c0 = cb + c4 * 4;
    v += xv.x * ewT[(c0 + 0) * 33 + L];
    v += xv.y * ewT[(c0 + 1) * 33 + L];
    v += xv.z * ewT[(c0 + 2) * 33 + L];
    v += xv.w * ewT[(c0 + 3) * 33 + L];
  }
  v += __shfl_xor(v, 32);
  if (h == 0) xed[wv][L] = v;
  if (lane < 16) {
    int idx = 0; float best = s_out[n * 4 + 0];
    float c1 = s_out[n * 4 + 1]; if (c1 > best) { best = c1; idx = 1; }
    float c2 = s_out[n * 4 + 2]; if (c2 > best) { best = c2; idx = 2; }
    float c3 = s_out[n * 4 + 3]; if (c3 > best) { best = c3; idx = 3; }
    float racc = l3bs[lane];
#pragma unroll
    for (int j = 0; j < 32; ++j) racc += xed[wv][j] * l3T[j * 17 + lane];
    const float* sxr = sx2 + idx * 16;
#pragma unroll
    for (int j = 0; j < 16; ++j) racc += sxr[j] * l3T[(32 + j) * 17 + lane];
    if (bf) ((__hip_bfloat16*)out)[n * 16 + lane] = __float2bfloat16(racc);
    else    ((float*)out)[n * 16 + lane] = racc;
  }
}

extern "C" void kernel_launch(void* const* d_in, const int* in_sizes, int n_in,
                              void* d_out, int out_size, void* d_ws, size_t ws_size,
                              hipStream_t stream) {
  float* F = (float*)d_ws;
  int* I = (int*)d_ws;

  static const int pcnt[29] = {6400, 4096, 4096, 64, 4096, 4096, 64, 256, 256, 4, 528, 4,
                               4096, 4096, 64, 4096, 4096, 64, 4096, 4096, 64,
                               12288, 64, 1024, 16, 6144, 32, 768, 16};
  int poff[29];
  { int a = 0; for (int i = 0; i < 29; ++i) { poff[i] = a; a += pcnt[i]; } }

  PtrTab tab;
  for (int i = 0; i < 29; ++i) { tab.src[i] = d_in[i]; tab.off[i] = poff[i]; tab.cnt[i] = pcnt[i]; }

  const int* ei = (const int*)d_in[29];
  const int* nt = (const int*)d_in[30];

  int* deg = I + W_DEG;
  int* cur = I + W_CUR;
  int* rowptr = I + W_ROWPTR;
  int* col = I + W_COL;
  int* flag = I + W_FLAG;
  float* st = F + W_STATS;
  float* sxacc = F + W_SXACC;
  float* x0 = F + W_X0;
  float* zp1 = F + W_ZP1; float* zp2 = F + W_ZP2; float* zp3 = F + W_ZP3;
  float* ze1 = F + W_ZE1; float* ze2 = F + W_ZE2; float* ze3 = F + W_ZE3;
  float* sbuf = F + W_S;
  float* sx2 = F + W_SX2;
  float* P = F + W_PAR;
#define PP(i) (P + poff[i])

  hipMemsetAsync(d_ws, 0, (size_t)W_ZEND * 4, stream);
  k_detect<<<1, 256, 0, stream>>>(d_in[0], flag);
  k_convert<<<29, 256, 0, stream>>>(tab, P, flag);
  k_deg<<<750, 256, 0, stream>>>(ei, deg);
  k_scan<<<1, 1024, 0, stream>>>(deg, rowptr);
  k_scatter<<<750, 256, 0, stream>>>(ei, rowptr, cur, col);
  k_emb<<<1500, 256, 0, stream>>>(PP(0), nt, x0);

  // pool GNN
  k_sage<64><<<1500, 256, 0, stream>>>(x0, nullptr, PP(1), PP(2), PP(3), rowptr, col, zp1, st + 0 * 128);
  k_sage<64><<<1500, 256, 0, stream>>>(zp1, st + 0 * 128, PP(4), PP(5), PP(6), rowptr, col, zp2, st + 1 * 128);
  k_sage<4><<<1500, 256, 0, stream>>>(zp2, st + 1 * 128, PP(7), PP(8), PP(9), rowptr, col, zp3, st + 2 * 128);
  // embed GNN
  k_sage<64><<<1500, 256, 0, stream>>>(x0, nullptr, PP(12), PP(13), PP(14), rowptr, col, ze1, st + 3 * 128);
  k_sage<64><<<1500, 256, 0, stream>>>(ze1, st + 3 * 128, PP(15), PP(16), PP(17), rowptr, col, ze2, st + 4 * 128);
  k_sage<64><<<1500, 256, 0, stream>>>(ze2, st + 4 * 128, PP(18), PP(19), PP(20), rowptr, col, ze3, st + 5 * 128);

  k_pool<<<750, 256, 0, stream>>>(zp1, zp2, zp3, st + 0 * 128, st + 1 * 128, st + 2 * 128,
                                  ze1, ze2, ze3, st + 3 * 128, st + 4 * 128, st + 5 * 128,
                                  PP(10), PP(11), sbuf, sxacc);
  k_mlp<<<1, 256, 0, stream>>>(sxacc, PP(21), PP(22), PP(23), PP(24), sx2);
  k_final<<<1500, 256, 0, stream>>>(ze1, ze2, ze3, st + 3 * 128, st + 4 * 128, st + 5 * 128,
                                    PP(25), PP(26), PP(27), PP(28), sbuf, sx2, flag, d_out);
}

// Round 3
// 334.697 us; speedup vs baseline: 1.6330x; 1.3452x over previous
//
#include <hip/hip_runtime.h>
#include <hip/hip_bf16.h>

#define NN 6000
#define EE 192000

// ---------------- workspace layout (in 4-byte words) ----------------
#define W_DEG     0
#define W_CUR     6000
#define W_STATS   12000        // 6 slots x 128 (sum[64], sumsq[64])
#define W_SXACC   12768        // 4 x 192
#define W_ZEND    13536
#define W_FLAG    13536
#define W_ROWPTR  13540        // 6001
#define W_COL     19544        // 192000
#define W_X0      211544       // 6000*64
#define W_ZP1     595544
#define W_ZP2     979544
#define W_ZP3     1363544      // 6000*4
#define W_ZE1     1387544
#define W_ZE2     1771544
#define W_ZE3     2155544
#define W_S       2539544      // 6000*4
#define W_SX2     2563544      // 64
#define W_PAR     2563608      // fp32 param region

struct PtrTab {
  const void* src[29];
  int off[29];
  int cnt[29];
};

__device__ __forceinline__ float bf2f(unsigned short h) {
  return __uint_as_float(((unsigned)h) << 16);
}
__device__ __forceinline__ int rfl(int x) { return __builtin_amdgcn_readfirstlane(x); }

// ---- dtype detection ----
__global__ void k_detect(const void* emb, int* flag) {
  __shared__ int bad;
  if (threadIdx.x == 0) bad = 0;
  __syncthreads();
  const unsigned short* p = (const unsigned short*)emb;
  float v0 = bf2f(p[threadIdx.x]);
  float v1 = bf2f(p[threadIdx.x + 256]);
  if (!(fabsf(v0) <= 100.f) || !(fabsf(v1) <= 100.f)) bad = 1;
  __syncthreads();
  if (threadIdx.x == 0) flag[0] = bad ? 0 : 1;   // 1 = bf16 inputs, 0 = fp32
}

// ---- convert params to fp32 workspace ----
__global__ void k_convert(PtrTab tab, float* base, const int* flag) {
  int b = blockIdx.x;
  const void* s = tab.src[b];
  float* d = base + tab.off[b];
  int n = tab.cnt[b];
  bool bf = (flag[0] == 1);
  if (bf) {
    const unsigned short* sp = (const unsigned short*)s;
    for (int i = threadIdx.x; i < n; i += 256) d[i] = bf2f(sp[i]);
  } else {
    const float* sp = (const float*)s;
    for (int i = threadIdx.x; i < n; i += 256) d[i] = sp[i];
  }
}

// ---- CSR build ----
__global__ void k_deg(const int* __restrict__ ei, int* __restrict__ deg) {
  int e = blockIdx.x * 256 + threadIdx.x;
  if (e < EE) atomicAdd(&deg[ei[e]], 1);
}

__global__ void k_scan(const int* __restrict__ deg, int* __restrict__ rowptr) {
  __shared__ int part[1024];
  int t = threadIdx.x;
  int base = t * 6;
  int loc[6]; int s = 0;
#pragma unroll
  for (int j = 0; j < 6; ++j) { int i = base + j; int v = (i < NN) ? deg[i] : 0; loc[j] = s; s += v; }
  part[t] = s;
  __syncthreads();
  for (int off = 1; off < 1024; off <<= 1) {
    int v = part[t];
    int add = (t >= off) ? part[t - off] : 0;
    __syncthreads();
    part[t] = v + add;
    __syncthreads();
  }
  int pre = (t == 0) ? 0 : part[t - 1];
#pragma unroll
  for (int j = 0; j < 6; ++j) { int i = base + j; if (i <= NN) rowptr[i] = pre + loc[j]; }
}

__global__ void k_scatter(const int* __restrict__ ei, const int* __restrict__ rowptr,
                          int* __restrict__ cur, int* __restrict__ col) {
  int e = blockIdx.x * 256 + threadIdx.x;
  if (e < EE) {
    int s = ei[e], d = ei[EE + e];
    int pos = atomicAdd(&cur[s], 1);
    col[rowptr[s] + pos] = d;
  }
}

// ---- embedding gather (float4): 375 blocks ----
__global__ void k_emb(const float* __restrict__ emb, const int* __restrict__ nt, float* __restrict__ x0) {
  int t = blockIdx.x * 256 + threadIdx.x;     // 96000 threads
  int i = t >> 4, q = t & 15;
  *(float4*)&x0[i * 64 + q * 4] = *(const float4*)&emb[nt[i] * 64 + q * 4];
}

// ---- fused DenseSAGE body: grid-stride waves, float4 gather, register stats ----
template <int OUT, bool HS>
__device__ __forceinline__ void sage_body(
    const float* __restrict__ in_z, const float* __restrict__ in_stats,
    const float* __restrict__ wr, const float* __restrict__ wl, const float* __restrict__ bias,
    const int* __restrict__ rowptr, const int* __restrict__ col,
    float* __restrict__ out_z, float* __restrict__ out_stats,
    int vb, int total_waves,
    float* __restrict__ wrT, float* __restrict__ wlT, float* __restrict__ bs,
    float (* __restrict__ vec)[2][64], float (* __restrict__ red)[2][64]) {
  int tid = threadIdx.x, lane = tid & 63, wv = tid >> 6;

  for (int i = tid; i < 64 * OUT; i += 256) {
    int f = i >> 6, k = i & 63;                 // wr row-major [OUT][64]
    wrT[k * (OUT + 1) + f] = wr[i];             // transposed + padded: conflict-free
    wlT[k * (OUT + 1) + f] = wl[i];
  }
  if (tid < OUT) bs[tid] = bias[tid];

  int quad = lane & 15, sub = lane >> 4;
  float m = 0.f, r = 1.f;
  float m4x = 0.f, m4y = 0.f, m4z = 0.f, m4w = 0.f;
  float r4x = 1.f, r4y = 1.f, r4z = 1.f, r4w = 1.f;
  if (HS) {
    float s = in_stats[lane], q = in_stats[64 + lane];
    m = s * (1.f / NN);
    r = rsqrtf(q * (1.f / NN) - m * m + 1e-5f);
    float4 s4 = *(const float4*)(in_stats + quad * 4);
    float4 q4 = *(const float4*)(in_stats + 64 + quad * 4);
    m4x = s4.x * (1.f / NN); m4y = s4.y * (1.f / NN); m4z = s4.z * (1.f / NN); m4w = s4.w * (1.f / NN);
    r4x = rsqrtf(q4.x * (1.f / NN) - m4x * m4x + 1e-5f);
    r4y = rsqrtf(q4.y * (1.f / NN) - m4y * m4y + 1e-5f);
    r4z = rsqrtf(q4.z * (1.f / NN) - m4z * m4z + 1e-5f);
    r4w = rsqrtf(q4.w * (1.f / NN) - m4w * m4w + 1e-5f);
  }
  __syncthreads();   // weights staged; no further barriers until epilogue

  float accs = 0.f, accq = 0.f;
  int ol = lane & (OUT - 1);
  int wave_id = vb * 4 + wv;
  for (int n = wave_id; n < NN; n += total_waves) {
    float x = (in_z[n * 64 + lane] - m) * r;
    int rs = rfl(rowptr[n]), re = rfl(rowptr[n + 1]);
    int cnt = re - rs;
    float szx = 0.f, szy = 0.f, szz = 0.f, szw = 0.f;
    for (int base = rs; base < re; base += 32) {
#pragma unroll
      for (int u = 0; u < 8; ++u) {
        int cidx = base + u * 4 + sub;
        bool ok = cidx < re;
        int cc = ok ? cidx : rs;                 // safe: loop entered => re > rs
        int j = col[cc];
        const float4 v = *(const float4*)(in_z + j * 64 + quad * 4);
        if (ok) { szx += v.x; szy += v.y; szz += v.z; szw += v.w; }
      }
    }
#pragma unroll
    for (int off = 16; off < 64; off <<= 1) {
      szx += __shfl_xor(szx, off);
      szy += __shfl_xor(szy, off);
      szz += __shfl_xor(szz, off);
      szw += __shfl_xor(szw, off);
    }
    float inv = 1.f / (float)(cnt > 0 ? cnt : 1);
    float fc = (float)cnt;
    if (sub == 0) {
      float4 a;
      a.x = (szx - fc * m4x) * r4x * inv;
      a.y = (szy - fc * m4y) * r4y * inv;
      a.z = (szz - fc * m4z) * r4z * inv;
      a.w = (szw - fc * m4w) * r4w * inv;
      *(float4*)&vec[wv][0][quad * 4] = a;       // 16 lanes x b128, 2-way banks: free
    }
    vec[wv][1][lane] = x;
    // wave-synchronous LDS write->read (in-order DS pipe within a wave)
    float y = bs[ol];
    const float* va = &vec[wv][0][0];
    const float* vx = &vec[wv][1][0];
#pragma unroll
    for (int kk = 0; kk < 16; ++kk) {
      const float4 a4 = *(const float4*)(va + kk * 4);   // broadcast
      const float4 x4 = *(const float4*)(vx + kk * 4);
      int k0 = kk * 4;
      y += a4.x * wrT[(k0 + 0) * (OUT + 1) + ol] + x4.x * wlT[(k0 + 0) * (OUT + 1) + ol];
      y += a4.y * wrT[(k0 + 1) * (OUT + 1) + ol] + x4.y * wlT[(k0 + 1) * (OUT + 1) + ol];
      y += a4.z * wrT[(k0 + 2) * (OUT + 1) + ol] + x4.z * wlT[(k0 + 2) * (OUT + 1) + ol];
      y += a4.w * wrT[(k0 + 3) * (OUT + 1) + ol] + x4.w * wlT[(k0 + 3) * (OUT + 1) + ol];
    }
    float z = fmaxf(y, 0.f);
    if (lane < OUT) {
      out_z[n * OUT + lane] = z;
      accs += z; accq += z * z;
    }
  }
  if (lane < OUT) { red[wv][0][lane] = accs; red[wv][1][lane] = accq; }
  __syncthreads();
  if (tid < OUT) {
    float s = red[0][0][tid] + red[1][0][tid] + red[2][0][tid] + red[3][0][tid];
    float q = red[0][1][tid] + red[1][1][tid] + red[2][1][tid] + red[3][1][tid];
    atomicAdd(&out_stats[tid], s);
    atomicAdd(&out_stats[64 + tid], q);
  }
}

// dual-path sage: blocks [0,G) run path A, [G,2G) run path B (independent chains)
template <int OUTA, int OUTB, bool HS>
__global__ __launch_bounds__(256, 4) void k_dual(
    const float* __restrict__ inA, const float* __restrict__ stA,
    const float* __restrict__ wrA, const float* __restrict__ wlA, const float* __restrict__ bA,
    float* __restrict__ outA, float* __restrict__ ostA,
    const float* __restrict__ inB, const float* __restrict__ stB,
    const float* __restrict__ wrB, const float* __restrict__ wlB, const float* __restrict__ bB,
    float* __restrict__ outB, float* __restrict__ ostB,
    const int* __restrict__ rowptr, const int* __restrict__ col, int G) {
  __shared__ float wrT[64 * 65];
  __shared__ float wlT[64 * 65];
  __shared__ float bs[64];
  __shared__ float vec[4][2][64];
  __shared__ float red[4][2][64];
  if ((int)blockIdx.x < G)
    sage_body<OUTA, HS>(inA, stA, wrA, wlA, bA, rowptr, col, outA, ostA,
                        blockIdx.x, G * 4, wrT, wlT, bs, vec, red);
  else
    sage_body<OUTB, HS>(inB, stB, wrB, wlB, bB, rowptr, col, outB, ostB,
                        blockIdx.x - G, G * 4, wrT, wlT, bs, vec, red);
}

// ---- pool head: grid 375 blocks, 4 nodes per wave ----
__global__ __launch_bounds__(256) void k_pool(
    const float* __restrict__ zp1, const float* __restrict__ zp2, const float* __restrict__ zp3,
    const float* __restrict__ sp1, const float* __restrict__ sp2, const float* __restrict__ sp3,
    const float* __restrict__ ze1, const float* __restrict__ ze2, const float* __restrict__ ze3,
    const float* __restrict__ se1, const float* __restrict__ se2, const float* __restrict__ se3,
    const float* __restrict__ plw, const float* __restrict__ plb,
    float* __restrict__ s_out, float* __restrict__ sx_acc) {
  __shared__ float red[4][12][64];
  int tid = threadIdx.x, lane = tid & 63, wv = tid >> 6;

  float mp1 = sp1[lane] * (1.f / NN); float rp1 = rsqrtf(sp1[64 + lane] * (1.f / NN) - mp1 * mp1 + 1e-5f);
  float mp2 = sp2[lane] * (1.f / NN); float rp2 = rsqrtf(sp2[64 + lane] * (1.f / NN) - mp2 * mp2 + 1e-5f);
  float mp3 = 0.f, rp3 = 1.f;
  if (lane < 4) { mp3 = sp3[lane] * (1.f / NN); rp3 = rsqrtf(sp3[64 + lane] * (1.f / NN) - mp3 * mp3 + 1e-5f); }
  float me1 = se1[lane] * (1.f / NN); float re1 = rsqrtf(se1[64 + lane] * (1.f / NN) - me1 * me1 + 1e-5f);
  float me2 = se2[lane] * (1.f / NN); float re2 = rsqrtf(se2[64 + lane] * (1.f / NN) - me2 * me2 + 1e-5f);
  float me3 = se3[lane] * (1.f / NN); float re3 = rsqrtf(se3[64 + lane] * (1.f / NN) - me3 * me3 + 1e-5f);

  float w0a = plw[0 * 132 + lane], w0b = plw[0 * 132 + 64 + lane], w0c = (lane < 4) ? plw[0 * 132 + 128 + lane] : 0.f;
  float w1a = plw[1 * 132 + lane], w1b = plw[1 * 132 + 64 + lane], w1c = (lane < 4) ? plw[1 * 132 + 128 + lane] : 0.f;
  float w2a = plw[2 * 132 + lane], w2b = plw[2 * 132 + 64 + lane], w2c = (lane < 4) ? plw[2 * 132 + 128 + lane] : 0.f;
  float w3a = plw[3 * 132 + lane], w3b = plw[3 * 132 + 64 + lane], w3c = (lane < 4) ? plw[3 * 132 + 128 + lane] : 0.f;
  float pb0 = plb[0], pb1v = plb[1], pb2v = plb[2], pb3v = plb[3];

  float acc[12];
#pragma unroll
  for (int u = 0; u < 12; ++u) acc[u] = 0.f;

  int wave_id = blockIdx.x * 4 + wv;       // 0..1499
  for (int n = wave_id; n < NN; n += 1500) {
    float a = (zp1[n * 64 + lane] - mp1) * rp1;
    float b = (zp2[n * 64 + lane] - mp2) * rp2;
    float c = (lane < 4) ? ((zp3[n * 4 + lane] - mp3) * rp3) : 0.f;
    float p0 = a * w0a + b * w0b + c * w0c;
    float p1 = a * w1a + b * w1b + c * w1c;
    float p2 = a * w2a + b * w2b + c * w2c;
    float p3 = a * w3a + b * w3b + c * w3c;
#pragma unroll
    for (int off = 1; off < 64; off <<= 1) {
      p0 += __shfl_xor(p0, off);
      p1 += __shfl_xor(p1, off);
      p2 += __shfl_xor(p2, off);
      p3 += __shfl_xor(p3, off);
    }
    float s0 = fmaxf(p0 + pb0, 0.f), s1 = fmaxf(p1 + pb1v, 0.f);
    float s2 = fmaxf(p2 + pb2v, 0.f), s3 = fmaxf(p3 + pb3v, 0.f);
    if (lane < 4) {
      float sv = (lane == 0) ? s0 : (lane == 1) ? s1 : (lane == 2) ? s2 : s3;
      s_out[n * 4 + lane] = sv;
    }
    float mx = fmaxf(fmaxf(s0, s1), fmaxf(s2, s3));
    float e0 = __expf(s0 - mx), e1 = __expf(s1 - mx), e2 = __expf(s2 - mx), e3 = __expf(s3 - mx);
    float inv = 1.f / (e0 + e1 + e2 + e3);
    e0 *= inv; e1 *= inv; e2 *= inv; e3 *= inv;
    float x1 = (ze1[n * 64 + lane] - me1) * re1;
    float x2 = (ze2[n * 64 + lane] - me2) * re2;
    float x3 = (ze3[n * 64 + lane] - me3) * re3;
    acc[0] += e0 * x1; acc[1] += e0 * x2; acc[2] += e0 * x3;
    acc[3] += e1 * x1; acc[4] += e1 * x2; acc[5] += e1 * x3;
    acc[6] += e2 * x1; acc[7] += e2 * x2; acc[8] += e2 * x3;
    acc[9] += e3 * x1; acc[10] += e3 * x2; acc[11] += e3 * x3;
  }
#pragma unroll
  for (int u = 0; u < 12; ++u) red[wv][u][lane] = acc[u];
  __syncthreads();
  for (int u = tid; u < 768; u += 256) {
    int f = u & 63, q = u >> 6;
    float v = red[0][q][f] + red[1][q][f] + red[2][q][f] + red[3][q][f];
    int k = q / 3, slot = q - 3 * k;
    atomicAdd(&sx_acc[k * 192 + slot * 64 + f], v);
  }
}

// ---- cluster MLP ----
__global__ void k_mlp(const float* __restrict__ sx, const float* __restrict__ l1w, const float* __restrict__ l1b,
                      const float* __restrict__ l2w, const float* __restrict__ l2b, float* __restrict__ sx2) {
  __shared__ float tl[4][64];
  int tid = threadIdx.x;
  int k = tid >> 6, f = tid & 63;
  float v = l1b[f];
  for (int c = 0; c < 192; ++c) v += sx[k * 192 + c] * l1w[f * 192 + c];
  tl[k][f] = fmaxf(v, 0.f);
  __syncthreads();
  if (tid < 64) {
    int kk = tid >> 4, o = tid & 15;
    float u = l2b[o];
#pragma unroll
    for (int j = 0; j < 64; ++j) u += tl[kk][j] * l2w[o * 64 + j];
    sx2[kk * 16 + o] = u;
  }
}

// ---- final: grid 512 blocks, grid-stride waves (~3 nodes each) ----
__global__ __launch_bounds__(256) void k_final(
    const float* __restrict__ ze1, const float* __restrict__ ze2, const float* __restrict__ ze3,
    const float* __restrict__ se1, const float* __restrict__ se2, const float* __restrict__ se3,
    const float* __restrict__ ew, const float* __restrict__ ebv,
    const float* __restrict__ l3w, const float* __restrict__ l3b,
    const float* __restrict__ s_out, const float* __restrict__ sx2,
    const int* __restrict__ flag, void* __restrict__ out) {
  __shared__ float ewT[192 * 33];          // padded
  __shared__ float l3T[48 * 17];
  __shared__ float ebs[32], l3bs[16];
  __shared__ float xev[4][192];
  __shared__ float xed[4][32];
  int tid = threadIdx.x, lane = tid & 63, wv = tid >> 6;

  for (int i = tid; i < 6144; i += 256) { int cp = i / 192, c = i - cp * 192; ewT[c * 33 + cp] = ew[i]; }
  for (int i = tid; i < 768; i += 256) { int o = i / 48, j = i - o * 48; l3T[j * 17 + o] = l3w[i]; }
  if (tid < 32) ebs[tid] = ebv[tid];
  if (tid < 16) l3bs[tid] = l3b[tid];

  float me1 = se1[lane] * (1.f / NN); float re1 = rsqrtf(se1[64 + lane] * (1.f / NN) - me1 * me1 + 1e-5f);
  float me2 = se2[lane] * (1.f / NN); float re2 = rsqrtf(se2[64 + lane] * (1.f / NN) - me2 * me2 + 1e-5f);
  float me3 = se3[lane] * (1.f / NN); float re3 = rsqrtf(se3[64 + lane] * (1.f / NN) - me3 * me3 + 1e-5f);
  bool bf = (flag[0] == 1);
  __syncthreads();   // staging barrier; body is wave-private

  int h = lane >> 5, L = lane & 31;
  int wave_id = blockIdx.x * 4 + wv;       // 0..2047
  for (int n = wave_id; n < NN; n += 2048) {
    float x1 = (ze1[n * 64 + lane] - me1) * re1;
    float x2 = (ze2[n * 64 + lane] - me2) * re2;
    float x3 = (ze3[n * 64 + lane] - me3) * re3;
    xev[wv][lane] = x1;
    xev[wv][64 + lane] = x2;
    xev[wv][128 + lane] = x3;
    float v = (h == 0) ? ebs[L] : 0.f;
    int cb = h * 96;
#pragma unroll
    for (int c4 = 0; c4 < 24; ++c4) {
      const float4 xv = *(const float4*)&xev[wv][cb + c4 * 4];
      int c0 = cb + c4 * 4;
      v += xv.x * ewT[(c0 + 0) * 33 + L];
      v += xv.y * ewT[(c0 + 1) * 33 + L];
      v += xv.z * ewT[(c0 + 2) * 33 + L];
      v += xv.w * ewT[(c0 + 3) * 33 + L];
    }
    v += __shfl_xor(v, 32);
    if (h == 0) xed[wv][L] = v;
    if (lane < 16) {
      int idx = 0; float best = s_out[n * 4 + 0];
      float c1 = s_out[n * 4 + 1]; if (c1 > best) { best = c1; idx = 1; }
      float c2 = s_out[n * 4 + 2]; if (c2 > best) { best = c2; idx = 2; }
      float c3 = s_out[n * 4 + 3]; if (c3 > best) { best = c3; idx = 3; }
      float racc = l3bs[lane];
#pragma unroll
      for (int j = 0; j < 32; ++j) racc += xed[wv][j] * l3T[j * 17 + lane];
      const float* sxr = sx2 + idx * 16;
#pragma unroll
      for (int j = 0; j < 16; ++j) racc += sxr[j] * l3T[(32 + j) * 17 + lane];
      if (bf) ((__hip_bfloat16*)out)[n * 16 + lane] = __float2bfloat16(racc);
      else    ((float*)out)[n * 16 + lane] = racc;
    }
  }
}

extern "C" void kernel_launch(void* const* d_in, const int* in_sizes, int n_in,
                              void* d_out, int out_size, void* d_ws, size_t ws_size,
                              hipStream_t stream) {
  float* F = (float*)d_ws;
  int* I = (int*)d_ws;

  static const int pcnt[29] = {6400, 4096, 4096, 64, 4096, 4096, 64, 256, 256, 4, 528, 4,
                               4096, 4096, 64, 4096, 4096, 64, 4096, 4096, 64,
                               12288, 64, 1024, 16, 6144, 32, 768, 16};
  int poff[29];
  { int a = 0; for (int i = 0; i < 29; ++i) { poff[i] = a; a += pcnt[i]; } }

  PtrTab tab;
  for (int i = 0; i < 29; ++i) { tab.src[i] = d_in[i]; tab.off[i] = poff[i]; tab.cnt[i] = pcnt[i]; }

  const int* ei = (const int*)d_in[29];
  const int* nt = (const int*)d_in[30];

  int* deg = I + W_DEG;
  int* cur = I + W_CUR;
  int* rowptr = I + W_ROWPTR;
  int* col = I + W_COL;
  int* flag = I + W_FLAG;
  float* st = F + W_STATS;
  float* sxacc = F + W_SXACC;
  float* x0 = F + W_X0;
  float* zp1 = F + W_ZP1; float* zp2 = F + W_ZP2; float* zp3 = F + W_ZP3;
  float* ze1 = F + W_ZE1; float* ze2 = F + W_ZE2; float* ze3 = F + W_ZE3;
  float* sbuf = F + W_S;
  float* sx2 = F + W_SX2;
  float* P = F + W_PAR;
#define PP(i) (P + poff[i])

  hipMemsetAsync(d_ws, 0, (size_t)W_ZEND * 4, stream);
  k_detect<<<1, 256, 0, stream>>>(d_in[0], flag);
  k_convert<<<29, 256, 0, stream>>>(tab, P, flag);
  k_deg<<<750, 256, 0, stream>>>(ei, deg);
  k_scan<<<1, 1024, 0, stream>>>(deg, rowptr);
  k_scatter<<<750, 256, 0, stream>>>(ei, rowptr, cur, col);
  k_emb<<<375, 256, 0, stream>>>(PP(0), nt, x0);

  // layer 1 (pool & embed share input x0, no input BN)
  k_dual<64, 64, false><<<1024, 256, 0, stream>>>(
      x0, nullptr, PP(1), PP(2), PP(3), zp1, st + 0 * 128,
      x0, nullptr, PP(12), PP(13), PP(14), ze1, st + 3 * 128,
      rowptr, col, 512);
  // layer 2
  k_dual<64, 64, true><<<1024, 256, 0, stream>>>(
      zp1, st + 0 * 128, PP(4), PP(5), PP(6), zp2, st + 1 * 128,
      ze1, st + 3 * 128, PP(15), PP(16), PP(17), ze2, st + 4 * 128,
      rowptr, col, 512);
  // layer 3
  k_dual<4, 64, true><<<1024, 256, 0, stream>>>(
      zp2, st + 1 * 128, PP(7), PP(8), PP(9), zp3, st + 2 * 128,
      ze2, st + 4 * 128, PP(18), PP(19), PP(20), ze3, st + 5 * 128,
      rowptr, col, 512);

  k_pool<<<375, 256, 0, stream>>>(zp1, zp2, zp3, st + 0 * 128, st + 1 * 128, st + 2 * 128,
                                  ze1, ze2, ze3, st + 3 * 128, st + 4 * 128, st + 5 * 128,
                                  PP(10), PP(11), sbuf, sxacc);
  k_mlp<<<1, 256, 0, stream>>>(sxacc, PP(21), PP(22), PP(23), PP(24), sx2);
  k_final<<<512, 256, 0, stream>>>(ze1, ze2, ze3, st + 3 * 128, st + 4 * 128, st + 5 * 128,
                                   PP(25), PP(26), PP(27), PP(28), sbuf, sx2, flag, d_out);
}